// Round 16
// baseline (199.328 us; speedup 1.0000x reference)
//
#include <hip/hip_runtime.h>

typedef _Float16 half8 __attribute__((ext_vector_type(8)));
typedef _Float16 half4 __attribute__((ext_vector_type(4)));
typedef _Float16 h2    __attribute__((ext_vector_type(2)));
typedef __fp16  fp16x2 __attribute__((ext_vector_type(2)));
typedef float floatx4 __attribute__((ext_vector_type(4)));
typedef float floatx2 __attribute__((ext_vector_type(2)));
typedef int   intx4  __attribute__((ext_vector_type(4)));
typedef intx4 intx4a __attribute__((aligned(8)));   // 8B-aligned 16B load

#define TPB 256
#define SCALE   8192.0f            // 2^13: lifts O(1e-4) table values into e4m3 range
#define INVSC   0.0001220703125f   // 2^-13, folded into bilinear y-weights (exact)

// ---- fp8 row-pair tables: entry i = {tab[i], tab[i+res]} = 8B (2 dwords of
// 4x e4m3). Corners of cell c are P[c] (v00,v01) and P[c+1] (v10,v11),
// adjacent -> ONE 16B load per table per point. emb0 2.1MB + emb1 0.56MB
// L2-resident; emb2 2.1KB L1-resident.
#define N0E (512 * 512 + 1)
#define N1E (264 * 264 + 1)
#define N2E (16 * 16 + 2)

struct GAddr { int i00, i10, i01, i11; float wx, wy; };

__device__ __forceinline__ GAddr gaddr(int res, float u, float v) {
    float r = (float)res;
    float sx = u * r, sy = v * r;
    int x0 = (int)sx, y0 = (int)sy;            // truncation, matches astype(int32)
    float wx = sx - (float)x0, wy = sy - (float)y0;
    int x1 = min(x0 + 1, res), y1 = min(y0 + 1, res);
    GAddr g;
    g.i00 = y0 * res + x0;  g.i10 = y0 * res + x1;   // reference stride = res
    g.i01 = y1 * res + x0;  g.i11 = y1 * res + x1;
    g.wx = wx; g.wy = wy;
    return g;
}

struct GQ { int c; float wx, wy; };

__device__ __forceinline__ GQ gq(int res, float u, float v) {
    float r = (float)res;
    float sx = u * r, sy = v * r;
    int x0 = (int)sx, y0 = (int)sy;
    GQ g; g.c = y0 * res + x0; g.wx = sx - (float)x0; g.wy = sy - (float)y0;
    return g;
}

__device__ __forceinline__ void bil4(float4 v00, float4 v10, float4 v01, float4 v11,
                                     float wx, float wy, float* f) {
    float omx = 1.0f - wx, omy = 1.0f - wy;
    f[0] = (v00.x * omx + v10.x * wx) * omy + (v01.x * omx + v11.x * wx) * wy;
    f[1] = (v00.y * omx + v10.y * wx) * omy + (v01.y * omx + v11.y * wx) * wy;
    f[2] = (v00.z * omx + v10.z * wx) * omy + (v01.z * omx + v11.z * wx) * wy;
    f[3] = (v00.w * omx + v10.w * wx) * omy + (v01.w * omx + v11.w * wx) * wy;
}

__device__ __forceinline__ h2 pk2(float a, float b) {
    fp16x2 r = __builtin_amdgcn_cvt_pkrtz(a, b);
    union { fp16x2 f; h2 h; } u; u.f = r; return u.h;
}

// fp8 quad decode + f32 bilinear. q = {v00,v01,v10,v11} dwords of 4x e4m3
// (scaled 2^13); omyS/wyS carry the exact 2^-13 down-scale.
__device__ __forceinline__ void bil8(intx4 q, float wx, float omyS, float wyS, float* f) {
    floatx2 a00 = __builtin_amdgcn_cvt_pk_f32_fp8(q.x, false);
    floatx2 b00 = __builtin_amdgcn_cvt_pk_f32_fp8(q.x, true);
    floatx2 a01 = __builtin_amdgcn_cvt_pk_f32_fp8(q.y, false);
    floatx2 b01 = __builtin_amdgcn_cvt_pk_f32_fp8(q.y, true);
    floatx2 a10 = __builtin_amdgcn_cvt_pk_f32_fp8(q.z, false);
    floatx2 b10 = __builtin_amdgcn_cvt_pk_f32_fp8(q.z, true);
    floatx2 a11 = __builtin_amdgcn_cvt_pk_f32_fp8(q.w, false);
    floatx2 b11 = __builtin_amdgcn_cvt_pk_f32_fp8(q.w, true);
    float omx = 1.0f - wx;
    f[0] = (a00[0] * omx + a10[0] * wx) * omyS + (a01[0] * omx + a11[0] * wx) * wyS;
    f[1] = (a00[1] * omx + a10[1] * wx) * omyS + (a01[1] * omx + a11[1] * wx) * wyS;
    f[2] = (b00[0] * omx + b10[0] * wx) * omyS + (b01[0] * omx + b11[0] * wx) * wyS;
    f[3] = (b00[1] * omx + b10[1] * wx) * omyS + (b01[1] * omx + b11[1] * wx) * wyS;
}

// packed relu: cvt first, then v_pk_max_f16 vs 0.
__device__ __forceinline__ half4 relu_pk4(float a, float b, float c, float d) {
    union { half4 v; h2 p[2]; } u;
    u.p[0] = pk2(a, b);
    u.p[1] = pk2(c, d);
    half4 z = {(_Float16)0, (_Float16)0, (_Float16)0, (_Float16)0};
    return __builtin_elementwise_max(u.v, z);
}

// f32 relu variant for the fallback kernel (kept identical to validated r3).
__device__ __forceinline__ half4 relu_pk4f(float a, float b, float c, float d) {
    union { half4 v; fp16x2 p[2]; } u;
    u.p[0] = __builtin_amdgcn_cvt_pkrtz(fmaxf(a, 0.0f), fmaxf(b, 0.0f));
    u.p[1] = __builtin_amdgcn_cvt_pkrtz(fmaxf(c, 0.0f), fmaxf(d, 0.0f));
    return u.v;
}

// ---- per-launch pack. ws layout (int2 units): [0,N0E) t0 | +N1E t1 | +N2E t2.
__global__ void pack_tables(const float4* __restrict__ e0,
                            const float4* __restrict__ e1,
                            const float4* __restrict__ e2,
                            int* __restrict__ w)
{
    int i = blockIdx.x * blockDim.x + threadIdx.x;
    const float4* src; int res, base, c;
    if (i < N0E)                       { src = e0; res = 512; base = 0;          c = i; }
    else if (i < N0E + N1E)            { src = e1; res = 264; base = N0E;        c = i - N0E; }
    else if (i < N0E + N1E + N2E)      { src = e2; res = 16;  base = N0E + N1E;  c = i - N0E - N1E; }
    else return;
    float4 A = src[c];                 // sources verified in-bounds per table
    float4 C = src[c + res];
    int d0 = __builtin_amdgcn_cvt_pk_fp8_f32(A.x * SCALE, A.y * SCALE, 0, false);
    d0     = __builtin_amdgcn_cvt_pk_fp8_f32(A.z * SCALE, A.w * SCALE, d0, true);
    int d1 = __builtin_amdgcn_cvt_pk_fp8_f32(C.x * SCALE, C.y * SCALE, 0, false);
    d1     = __builtin_amdgcn_cvt_pk_fp8_f32(C.z * SCALE, C.w * SCALE, d1, true);
    w[2 * (base + c)]     = d0;
    w[2 * (base + c) + 1] = d1;
}

// r16: DISCRIMINATING EXPERIMENT for the 4-waves question. r14's failure has
// two candidate causes: (H1) 4x40KB=160KB exact-fit fails on driver LDS
// reserve; (H2) the (256,3) compiler parks the unified allocation near the
// 170-reg budget, capping 3 waves/SIMD regardless of LDS. r16 moves w2 back
// into registers (r0-r2 pattern, +32 regs: 76+32+~20acc ~= 128 < 170 budget,
// NOT the thrice-spilled 128-budget config) and deletes w2l -> LDS 32KB/block
// -> 4x32=128KB, far under any reserve. Grid 1024. H1 -> occupancy ~37,
// dur ~85-92. H2 -> occupancy ~28, dur ~parity -> declare roofline on r13.
__global__ __launch_bounds__(TPB, 3) void dgn_mfma(
    const float* __restrict__ x,
    const int2*  __restrict__ tabs,
    const float*  __restrict__ w1, const float* __restrict__ b1,
    const float*  __restrict__ w2, const float* __restrict__ b2,
    const float*  __restrict__ w3, const float* __restrict__ b3,
    float*        __restrict__ out, int npts)
{
    __shared__ __align__(16) _Float16 smem[4 * 4096];   // 4 waves * 8KB, wave-private

    const int2* p0 = tabs;
    const int2* p1 = tabs + N0E;
    const int2* p2 = tabs + N0E + N1E;

    const int tid  = threadIdx.x;
    const int lane = tid & 63;
    const int wv   = tid >> 6;
    const int l15  = lane & 15;
    const int quad = lane >> 4;

    // ---- persistent weight fragments (w1, w2, w3 all in registers).
    // w1 K-permutation: slot k<12 -> row k+1 (features), slot 12 -> row 0
    // (idf), slots 13-15 -> zero. ----
    half8 w1f[4];
    #pragma unroll
    for (int nt = 0; nt < 4; ++nt)
        #pragma unroll
        for (int j = 0; j < 8; ++j) {
            int k = quad * 8 + j;
            int row = (k < 12) ? (k + 1) : ((k == 12) ? 0 : -1);
            w1f[nt][j] = (row >= 0) ? (_Float16)w1[row * 64 + nt * 16 + l15] : (_Float16)0.0f;
        }
    float b1v[4], b2v[4];
    #pragma unroll
    for (int nt = 0; nt < 4; ++nt) { b1v[nt] = b1[nt * 16 + l15]; b2v[nt] = b2[nt * 16 + l15]; }
    half8 w2f[4][2];
    #pragma unroll
    for (int nt = 0; nt < 4; ++nt)
        #pragma unroll
        for (int ks = 0; ks < 2; ++ks)
            #pragma unroll
            for (int j = 0; j < 8; ++j) {
                int s  = ks * 32 + quad * 8 + j;
                int oh = ((s & 3) << 4) | (s >> 2);     // sigma^{-1}
                w2f[nt][ks][j] = (_Float16)w2[oh * 64 + nt * 16 + l15];
            }
    half8 w3f[2];
    #pragma unroll
    for (int ks = 0; ks < 2; ++ks)
        #pragma unroll
        for (int j = 0; j < 8; ++j) {
            int s  = ks * 32 + quad * 8 + j;
            int oh = ((s & 3) << 4) | (s >> 2);
            w3f[ks][j] = (l15 < 3) ? (_Float16)w3[oh * 3 + l15] : (_Float16)0.0f;
        }
    const float qsel = (quad == 0) ? 1.0f : 0.0f;
    const float qb30 = qsel * b3[0], qb31 = qsel * b3[1], qb32 = qsel * b3[2];

    // ---- precomputed LDS addresses (half-element units) ----
    const int bufh = wv * 4096;
    const int ewr0 = bufh + lane * 64 + ((lane & 7) ^ 0) * 8;
    const int ewr1 = bufh + lane * 64 + ((lane & 7) ^ 1) * 8;
    const int erd  = bufh + l15 * 64 + (quad ^ (l15 & 7)) * 8;          // quad<2 only
    int hwb[4];
    #pragma unroll
    for (int r = 0; r < 4; ++r) {
        int pr = quad * 4 + r;
        hwb[r] = bufh + pr * 64 + (((l15 >> 1) ^ (pr & 7)) * 8) + (l15 & 1) * 4;
    }
    int rd2[2];
    #pragma unroll
    for (int ks = 0; ks < 2; ++ks)
        rd2[ks] = bufh + l15 * 64 + (((ks * 4 + quad) ^ (l15 & 7)) * 8);

    const int ntiles = npts >> 8;
    const int gdim   = gridDim.x;

    // ---- prologue: tile-0 x + all three row-pair gathers in flight ----
    float cidf, cu, cv, wx0, wy0, wx1, wy1, wx2, wy2;
    intx4 t0q, t1q, t2q;
    {
        int pi = (blockIdx.x << 8) + (wv << 6) + lane;
        cidf = x[3 * pi]; cu = x[3 * pi + 1]; cv = x[3 * pi + 2];
        GQ g0 = gq(512, cu, cv); wx0 = g0.wx; wy0 = g0.wy;
        t0q = *(const intx4a*)&p0[g0.c];
        GQ g1 = gq(264, cu, cv); wx1 = g1.wx; wy1 = g1.wy;
        t1q = *(const intx4a*)&p1[g1.c];
        GQ g2 = gq(16, cu, cv); wx2 = g2.wx; wy2 = g2.wy;
        t2q = *(const intx4a*)&p2[g2.c];
    }

    for (int tile = blockIdx.x; tile < ntiles; tile += gdim) {
        // ---- features: fp8 decode + f32 lerp (2^-13 folded in y-weights) ----
        float f0[4], f1[4], f2[4];
        bil8(t0q, wx0, (1.0f - wy0) * INVSC, wy0 * INVSC, f0);
        bil8(t1q, wx1, (1.0f - wy1) * INVSC, wy1 * INVSC, f1);
        bil8(t2q, wx2, (1.0f - wy2) * INVSC, wy2 * INVSC, f2);
        // E pack: slots 0-11 = features, slot 12 = idf, 13-15 = 0
        union H8 { half8 v; h2 p[4]; } e0u, e1u;
        e0u.p[0] = pk2(f0[0], f0[1]); e0u.p[1] = pk2(f0[2], f0[3]);
        e0u.p[2] = pk2(f1[0], f1[1]); e0u.p[3] = pk2(f1[2], f1[3]);
        e1u.p[0] = pk2(f2[0], f2[1]); e1u.p[1] = pk2(f2[2], f2[3]);
        e1u.p[2] = pk2(cidf, 0.0f);   e1u.p[3] = pk2(0.0f, 0.0f);
        *(half8*)&smem[ewr0] = e0u.v;
        *(half8*)&smem[ewr1] = e1u.v;

        // ---- prefetch next tile's x (latency hidden by layer 1) ----
        int nxt = tile + gdim;
        int ptn = (((nxt < ntiles) ? nxt : tile) << 8) + (wv << 6) + lane;
        float nidf = x[3 * ptn], nu = x[3 * ptn + 1], nv = x[3 * ptn + 2];

        // ---- layer 1: K=32 (quads 2-3 feed zeros), bias in C-init ----
        #pragma unroll
        for (int mt = 0; mt < 4; ++mt) {
            half8 ea = { (_Float16)0, (_Float16)0, (_Float16)0, (_Float16)0,
                         (_Float16)0, (_Float16)0, (_Float16)0, (_Float16)0 };
            if (quad < 2) ea = *(const half8*)&smem[erd + mt * 1024];
            floatx4 acc[4];
            #pragma unroll
            for (int nt = 0; nt < 4; ++nt) {
                acc[nt] = (floatx4){ b1v[nt], b1v[nt], b1v[nt], b1v[nt] };
                acc[nt] = __builtin_amdgcn_mfma_f32_16x16x32_f16(ea, w1f[nt], acc[nt], 0, 0, 0);
            }
            #pragma unroll
            for (int r = 0; r < 4; ++r)
                *(half4*)&smem[hwb[r] + mt * 1024] =
                    relu_pk4(acc[0][r], acc[1][r], acc[2][r], acc[3][r]);
        }

        // ---- issue next tile's gathers (hidden by layers 2-3) ----
        float nwx0, nwy0, nwx1, nwy1, nwx2, nwy2;
        intx4 m0q, m1q, m2q;
        {
            GQ g0 = gq(512, nu, nv); nwx0 = g0.wx; nwy0 = g0.wy;
            m0q = *(const intx4a*)&p0[g0.c];
            GQ g1 = gq(264, nu, nv); nwx1 = g1.wx; nwy1 = g1.wy;
            m1q = *(const intx4a*)&p1[g1.c];
            GQ g2 = gq(16, nu, nv); nwx2 = g2.wx; nwy2 = g2.wy;
            m2q = *(const intx4a*)&p2[g2.c];
        }

        // ---- layer 2 (K=64), w2 fragments from registers ----
        #pragma unroll
        for (int mt = 0; mt < 4; ++mt) {
            floatx4 acc[4];
            #pragma unroll
            for (int nt = 0; nt < 4; ++nt)
                acc[nt] = (floatx4){ b2v[nt], b2v[nt], b2v[nt], b2v[nt] };
            #pragma unroll
            for (int ks = 0; ks < 2; ++ks) {
                half8 a2 = *(const half8*)&smem[rd2[ks] + mt * 1024];
                #pragma unroll
                for (int nt = 0; nt < 4; ++nt)
                    acc[nt] = __builtin_amdgcn_mfma_f32_16x16x32_f16(a2, w2f[nt][ks], acc[nt], 0, 0, 0);
            }
            #pragma unroll
            for (int r = 0; r < 4; ++r)
                *(half4*)&smem[hwb[r] + mt * 1024] =
                    relu_pk4(acc[0][r], acc[1][r], acc[2][r], acc[3][r]);
        }

        // ---- layer 3 (transposed) ----
        #pragma unroll
        for (int mt = 0; mt < 4; ++mt) {
            floatx4 acc3 = (floatx4){ qb30, qb31, qb32, 0.0f };
            #pragma unroll
            for (int ks = 0; ks < 2; ++ks) {
                half8 bfr = *(const half8*)&smem[rd2[ks] + mt * 1024];
                acc3 = __builtin_amdgcn_mfma_f32_16x16x32_f16(w3f[ks], bfr, acc3, 0, 0, 0);
            }
            if (quad == 0) {
                const int P = (tile << 8) + (wv << 6) + mt * 16 + l15;
                out[3 * P + 0] = acc3[0];
                out[3 * P + 1] = acc3[1];
                out[3 * P + 2] = acc3[2];
            }
        }

        // ---- rotate pipeline registers ----
        cidf = nidf; cu = nu; cv = nv;
        wx0 = nwx0; wy0 = nwy0; wx1 = nwx1; wy1 = nwy1; wx2 = nwx2; wy2 = nwy2;
        t0q = m0q; t1q = m1q; t2q = m2q;
    }
}

// ---- fallback (validated round-3 kernel, float4 gathers) for tiny ws ----
__global__ __launch_bounds__(TPB, 3) void dgn_mfma_fb(
    const float*  __restrict__ x,
    const float4* __restrict__ emb0,
    const float4* __restrict__ emb1,
    const float4* __restrict__ emb2,
    const float*  __restrict__ w1, const float* __restrict__ b1,
    const float*  __restrict__ w2, const float* __restrict__ b2,
    const float*  __restrict__ w3, const float* __restrict__ b3,
    float*        __restrict__ out, int npts)
{
    __shared__ __align__(16) _Float16 smem[4 * 4096];
    __shared__ __align__(16) _Float16 w2l[4096];

    const int tid  = threadIdx.x;
    const int lane = tid & 63;
    const int wv   = tid >> 6;
    const int l15  = lane & 15;
    const int quad = lane >> 4;

    for (int e = tid; e < 4096; e += TPB) {
        int nt = e >> 10, rem = e & 1023, lw = rem >> 6, s = rem & 63;
        int oh = ((s & 3) << 4) | (s >> 2);
        w2l[nt * 1024 + lw * 64 + (s ^ ((lw & 7) << 3))] =
            (_Float16)w2[oh * 64 + nt * 16 + lw];
    }
    __syncthreads();

    half8 w1f[4];
    #pragma unroll
    for (int nt = 0; nt < 4; ++nt)
        #pragma unroll
        for (int j = 0; j < 8; ++j) {
            int k = quad * 8 + j;
            w1f[nt][j] = (k < 13) ? (_Float16)w1[k * 64 + nt * 16 + l15] : (_Float16)0.0f;
        }
    float b1v[4], b2v[4];
    #pragma unroll
    for (int nt = 0; nt < 4; ++nt) { b1v[nt] = b1[nt * 16 + l15]; b2v[nt] = b2[nt * 16 + l15]; }
    half8 w3f[2];
    #pragma unroll
    for (int ks = 0; ks < 2; ++ks)
        #pragma unroll
        for (int j = 0; j < 8; ++j) {
            int s  = ks * 32 + quad * 8 + j;
            int oh = ((s & 3) << 4) | (s >> 2);
            w3f[ks][j] = (l15 < 3) ? (_Float16)w3[oh * 3 + l15] : (_Float16)0.0f;
        }
    const float qsel = (quad == 0) ? 1.0f : 0.0f;
    const float qb30 = qsel * b3[0], qb31 = qsel * b3[1], qb32 = qsel * b3[2];

    const int bufh = wv * 4096;
    const int ewr0 = bufh + lane * 64 + ((lane & 7) ^ 0) * 8;
    const int ewr1 = bufh + lane * 64 + ((lane & 7) ^ 1) * 8;
    const int erd  = bufh + l15 * 64 + (quad ^ (l15 & 7)) * 8;
    int hwb[4];
    #pragma unroll
    for (int r = 0; r < 4; ++r) {
        int pr = quad * 4 + r;
        hwb[r] = bufh + pr * 64 + (((l15 >> 1) ^ (pr & 7)) * 8) + (l15 & 1) * 4;
    }
    int rd2[2];
    #pragma unroll
    for (int ks = 0; ks < 2; ++ks)
        rd2[ks] = bufh + l15 * 64 + (((ks * 4 + quad) ^ (l15 & 7)) * 8);
    int w2a[2];
    #pragma unroll
    for (int ks = 0; ks < 2; ++ks)
        w2a[ks] = l15 * 64 + (((ks * 4 + quad) ^ (l15 & 7)) * 8);

    const int ntiles = npts >> 8;
    const int gdim   = gridDim.x;

    float cidf, cu, cv, wx0, wy0, wx1, wy1;
    float4 t00, t01, t02, t03, t10, t11, t12, t13;
    {
        int p0 = (blockIdx.x << 8) + (wv << 6) + lane;
        cidf = x[3 * p0]; cu = x[3 * p0 + 1]; cv = x[3 * p0 + 2];
        GAddr g0 = gaddr(512, cu, cv); wx0 = g0.wx; wy0 = g0.wy;
        t00 = emb0[g0.i00]; t01 = emb0[g0.i10]; t02 = emb0[g0.i01]; t03 = emb0[g0.i11];
        GAddr g1 = gaddr(264, cu, cv); wx1 = g1.wx; wy1 = g1.wy;
        t10 = emb1[g1.i00]; t11 = emb1[g1.i10]; t12 = emb1[g1.i01]; t13 = emb1[g1.i11];
    }

    for (int tile = blockIdx.x; tile < ntiles; tile += gdim) {
        float f[12];
        bil4(t00, t01, t02, t03, wx0, wy0, f);
        bil4(t10, t11, t12, t13, wx1, wy1, f + 4);
        {
            GAddr g2 = gaddr(16, cu, cv);
            bil4(emb2[g2.i00], emb2[g2.i10], emb2[g2.i01], emb2[g2.i11], g2.wx, g2.wy, f + 8);
        }
        union H8 { half8 v; fp16x2 p[4]; } e0u, e1u;
        e0u.p[0] = __builtin_amdgcn_cvt_pkrtz(cidf, f[0]);
        e0u.p[1] = __builtin_amdgcn_cvt_pkrtz(f[1], f[2]);
        e0u.p[2] = __builtin_amdgcn_cvt_pkrtz(f[3], f[4]);
        e0u.p[3] = __builtin_amdgcn_cvt_pkrtz(f[5], f[6]);
        e1u.p[0] = __builtin_amdgcn_cvt_pkrtz(f[7], f[8]);
        e1u.p[1] = __builtin_amdgcn_cvt_pkrtz(f[9], f[10]);
        e1u.p[2] = __builtin_amdgcn_cvt_pkrtz(f[11], 0.0f);
        e1u.p[3] = __builtin_amdgcn_cvt_pkrtz(0.0f, 0.0f);
        *(half8*)&smem[ewr0] = e0u.v;
        *(half8*)&smem[ewr1] = e1u.v;

        int nxt = tile + gdim;
        int ptn = (((nxt < ntiles) ? nxt : tile) << 8) + (wv << 6) + lane;
        float nidf = x[3 * ptn], nu = x[3 * ptn + 1], nv = x[3 * ptn + 2];

        #pragma unroll
        for (int mt = 0; mt < 4; ++mt) {
            half8 ea = { (_Float16)0, (_Float16)0, (_Float16)0, (_Float16)0,
                         (_Float16)0, (_Float16)0, (_Float16)0, (_Float16)0 };
            if (quad < 2) ea = *(const half8*)&smem[erd + mt * 1024];
            floatx4 acc[4];
            #pragma unroll
            for (int nt = 0; nt < 4; ++nt) {
                acc[nt] = (floatx4){ b1v[nt], b1v[nt], b1v[nt], b1v[nt] };
                acc[nt] = __builtin_amdgcn_mfma_f32_16x16x32_f16(ea, w1f[nt], acc[nt], 0, 0, 0);
            }
            #pragma unroll
            for (int r = 0; r < 4; ++r)
                *(half4*)&smem[hwb[r] + mt * 1024] =
                    relu_pk4f(acc[0][r], acc[1][r], acc[2][r], acc[3][r]);
        }

        float nwx0, nwy0, nwx1, nwy1;
        float4 n00, n01, n02, n03, n10, n11, n12, n13;
        {
            GAddr g0 = gaddr(512, nu, nv); nwx0 = g0.wx; nwy0 = g0.wy;
            n00 = emb0[g0.i00]; n01 = emb0[g0.i10]; n02 = emb0[g0.i01]; n03 = emb0[g0.i11];
            GAddr g1 = gaddr(264, nu, nv); nwx1 = g1.wx; nwy1 = g1.wy;
            n10 = emb1[g1.i00]; n11 = emb1[g1.i10]; n12 = emb1[g1.i01]; n13 = emb1[g1.i11];
        }

        half8 w2r[4][2];
        #pragma unroll
        for (int nt = 0; nt < 4; ++nt)
            #pragma unroll
            for (int ks = 0; ks < 2; ++ks)
                w2r[nt][ks] = *(const half8*)&w2l[nt * 1024 + w2a[ks]];
        #pragma unroll
        for (int mt = 0; mt < 4; ++mt) {
            floatx4 acc[4];
            #pragma unroll
            for (int nt = 0; nt < 4; ++nt)
                acc[nt] = (floatx4){ b2v[nt], b2v[nt], b2v[nt], b2v[nt] };
            #pragma unroll
            for (int ks = 0; ks < 2; ++ks) {
                half8 a2 = *(const half8*)&smem[rd2[ks] + mt * 1024];
                #pragma unroll
                for (int nt = 0; nt < 4; ++nt)
                    acc[nt] = __builtin_amdgcn_mfma_f32_16x16x32_f16(a2, w2r[nt][ks], acc[nt], 0, 0, 0);
            }
            #pragma unroll
            for (int r = 0; r < 4; ++r)
                *(half4*)&smem[hwb[r] + mt * 1024] =
                    relu_pk4f(acc[0][r], acc[1][r], acc[2][r], acc[3][r]);
        }

        #pragma unroll
        for (int mt = 0; mt < 4; ++mt) {
            floatx4 acc3 = (floatx4){ qb30, qb31, qb32, 0.0f };
            #pragma unroll
            for (int ks = 0; ks < 2; ++ks) {
                half8 bfr = *(const half8*)&smem[rd2[ks] + mt * 1024];
                acc3 = __builtin_amdgcn_mfma_f32_16x16x32_f16(w3f[ks], bfr, acc3, 0, 0, 0);
            }
            if (quad == 0) {
                const int P = (tile << 8) + (wv << 6) + mt * 16 + l15;
                out[3 * P + 0] = acc3[0];
                out[3 * P + 1] = acc3[1];
                out[3 * P + 2] = acc3[2];
            }
        }

        cidf = nidf; cu = nu; cv = nv;
        wx0 = nwx0; wy0 = nwy0; wx1 = nwx1; wy1 = nwy1;
        t00 = n00; t01 = n01; t02 = n02; t03 = n03;
        t10 = n10; t11 = n11; t12 = n12; t13 = n13;
    }
}

extern "C" void kernel_launch(void* const* d_in, const int* in_sizes, int n_in,
                              void* d_out, int out_size, void* d_ws, size_t ws_size,
                              hipStream_t stream) {
    const float*  x    = (const float*)  d_in[0];
    const float4* emb0 = (const float4*) d_in[1];
    const float4* emb1 = (const float4*) d_in[2];
    const float4* emb2 = (const float4*) d_in[3];
    const float*  w1   = (const float*)  d_in[4];
    const float*  b1   = (const float*)  d_in[5];
    const float*  w2   = (const float*)  d_in[6];
    const float*  b2   = (const float*)  d_in[7];
    const float*  w3   = (const float*)  d_in[8];
    const float*  b3   = (const float*)  d_in[9];
    float* out = (float*)d_out;

    int npts = in_sizes[0] / 3;
    const size_t need = (size_t)(N0E + N1E + N2E) * 8;   // ~2.7 MB

    if (d_ws != nullptr && ws_size >= need) {
        int work = N0E + N1E + N2E;
        pack_tables<<<(work + 255) / 256, 256, 0, stream>>>(emb0, emb1, emb2, (int*)d_ws);
        // grid 1024, LDS 32KB/block (4x32=128KB << 160KB): if r14's failure
        // was the exact-fit LDS reserve (H1), 4 blocks/CU now place.
        dgn_mfma<<<1024, TPB, 0, stream>>>(x, (const int2*)d_ws,
                                           w1, b1, w2, b2, w3, b3, out, npts);
    } else {
        dgn_mfma_fb<<<768, TPB, 0, stream>>>(x, emb0, emb1, emb2,
                                             w1, b1, w2, b2, w3, b3, out, npts);
    }
}

// Round 17
// 189.758 us; speedup vs baseline: 1.0504x; 1.0504x over previous
//
#include <hip/hip_runtime.h>

typedef _Float16 half8 __attribute__((ext_vector_type(8)));
typedef _Float16 half4 __attribute__((ext_vector_type(4)));
typedef _Float16 h2    __attribute__((ext_vector_type(2)));
typedef __fp16  fp16x2 __attribute__((ext_vector_type(2)));
typedef float floatx4 __attribute__((ext_vector_type(4)));
typedef float floatx2 __attribute__((ext_vector_type(2)));
typedef int   intx4  __attribute__((ext_vector_type(4)));
typedef intx4 intx4a __attribute__((aligned(8)));   // 8B-aligned 16B load

#define TPB 256
#define SCALE   8192.0f            // 2^13: lifts O(1e-4) table values into e4m3 range
#define INVSC   0.0001220703125f   // 2^-13, folded into bilinear y-weights (exact)

// ---- fp8 row-pair tables: entry i = {tab[i], tab[i+res]} = 8B (2 dwords of
// 4x e4m3). Corners of cell c are P[c] (v00,v01) and P[c+1] (v10,v11),
// adjacent -> ONE 16B load per table per point. emb0 2.1MB + emb1 0.56MB
// L2-resident; emb2 2.1KB L1-resident (out of LDS -> 0 bank conflicts).
#define N0E (512 * 512 + 1)
#define N1E (264 * 264 + 1)
#define N2E (16 * 16 + 2)

struct GAddr { int i00, i10, i01, i11; float wx, wy; };

__device__ __forceinline__ GAddr gaddr(int res, float u, float v) {
    float r = (float)res;
    float sx = u * r, sy = v * r;
    int x0 = (int)sx, y0 = (int)sy;            // truncation, matches astype(int32)
    float wx = sx - (float)x0, wy = sy - (float)y0;
    int x1 = min(x0 + 1, res), y1 = min(y0 + 1, res);
    GAddr g;
    g.i00 = y0 * res + x0;  g.i10 = y0 * res + x1;   // reference stride = res
    g.i01 = y1 * res + x0;  g.i11 = y1 * res + x1;
    g.wx = wx; g.wy = wy;
    return g;
}

struct GQ { int c; float wx, wy; };

__device__ __forceinline__ GQ gq(int res, float u, float v) {
    float r = (float)res;
    float sx = u * r, sy = v * r;
    int x0 = (int)sx, y0 = (int)sy;
    GQ g; g.c = y0 * res + x0; g.wx = sx - (float)x0; g.wy = sy - (float)y0;
    return g;
}

__device__ __forceinline__ void bil4(float4 v00, float4 v10, float4 v01, float4 v11,
                                     float wx, float wy, float* f) {
    float omx = 1.0f - wx, omy = 1.0f - wy;
    f[0] = (v00.x * omx + v10.x * wx) * omy + (v01.x * omx + v11.x * wx) * wy;
    f[1] = (v00.y * omx + v10.y * wx) * omy + (v01.y * omx + v11.y * wx) * wy;
    f[2] = (v00.z * omx + v10.z * wx) * omy + (v01.z * omx + v11.z * wx) * wy;
    f[3] = (v00.w * omx + v10.w * wx) * omy + (v01.w * omx + v11.w * wx) * wy;
}

__device__ __forceinline__ h2 pk2(float a, float b) {
    fp16x2 r = __builtin_amdgcn_cvt_pkrtz(a, b);
    union { fp16x2 f; h2 h; } u; u.f = r; return u.h;
}

// fp8 quad decode + f32 bilinear. q = {v00,v01,v10,v11} dwords of 4x e4m3
// (scaled 2^13); omyS/wyS carry the exact 2^-13 down-scale.
__device__ __forceinline__ void bil8(intx4 q, float wx, float omyS, float wyS, float* f) {
    floatx2 a00 = __builtin_amdgcn_cvt_pk_f32_fp8(q.x, false);
    floatx2 b00 = __builtin_amdgcn_cvt_pk_f32_fp8(q.x, true);
    floatx2 a01 = __builtin_amdgcn_cvt_pk_f32_fp8(q.y, false);
    floatx2 b01 = __builtin_amdgcn_cvt_pk_f32_fp8(q.y, true);
    floatx2 a10 = __builtin_amdgcn_cvt_pk_f32_fp8(q.z, false);
    floatx2 b10 = __builtin_amdgcn_cvt_pk_f32_fp8(q.z, true);
    floatx2 a11 = __builtin_amdgcn_cvt_pk_f32_fp8(q.w, false);
    floatx2 b11 = __builtin_amdgcn_cvt_pk_f32_fp8(q.w, true);
    float omx = 1.0f - wx;
    f[0] = (a00[0] * omx + a10[0] * wx) * omyS + (a01[0] * omx + a11[0] * wx) * wyS;
    f[1] = (a00[1] * omx + a10[1] * wx) * omyS + (a01[1] * omx + a11[1] * wx) * wyS;
    f[2] = (b00[0] * omx + b10[0] * wx) * omyS + (b01[0] * omx + b11[0] * wx) * wyS;
    f[3] = (b00[1] * omx + b10[1] * wx) * omyS + (b01[1] * omx + b11[1] * wx) * wyS;
}

// packed relu: cvt first, then v_pk_max_f16 vs 0.
__device__ __forceinline__ half4 relu_pk4(float a, float b, float c, float d) {
    union { half4 v; h2 p[2]; } u;
    u.p[0] = pk2(a, b);
    u.p[1] = pk2(c, d);
    half4 z = {(_Float16)0, (_Float16)0, (_Float16)0, (_Float16)0};
    return __builtin_elementwise_max(u.v, z);
}

// f32 relu variant for the fallback kernel (kept identical to validated r3).
__device__ __forceinline__ half4 relu_pk4f(float a, float b, float c, float d) {
    union { half4 v; fp16x2 p[2]; } u;
    u.p[0] = __builtin_amdgcn_cvt_pkrtz(fmaxf(a, 0.0f), fmaxf(b, 0.0f));
    u.p[1] = __builtin_amdgcn_cvt_pkrtz(fmaxf(c, 0.0f), fmaxf(d, 0.0f));
    return u.v;
}

// ---- per-launch pack. ws layout (int2 units): [0,N0E) t0 | +N1E t1 | +N2E t2.
__global__ void pack_tables(const float4* __restrict__ e0,
                            const float4* __restrict__ e1,
                            const float4* __restrict__ e2,
                            int* __restrict__ w)
{
    int i = blockIdx.x * blockDim.x + threadIdx.x;
    const float4* src; int res, base, c;
    if (i < N0E)                       { src = e0; res = 512; base = 0;          c = i; }
    else if (i < N0E + N1E)            { src = e1; res = 264; base = N0E;        c = i - N0E; }
    else if (i < N0E + N1E + N2E)      { src = e2; res = 16;  base = N0E + N1E;  c = i - N0E - N1E; }
    else return;
    float4 A = src[c];                 // sources verified in-bounds per table
    float4 C = src[c + res];
    int d0 = __builtin_amdgcn_cvt_pk_fp8_f32(A.x * SCALE, A.y * SCALE, 0, false);
    d0     = __builtin_amdgcn_cvt_pk_fp8_f32(A.z * SCALE, A.w * SCALE, d0, true);
    int d1 = __builtin_amdgcn_cvt_pk_fp8_f32(C.x * SCALE, C.y * SCALE, 0, false);
    d1     = __builtin_amdgcn_cvt_pk_fp8_f32(C.z * SCALE, C.w * SCALE, d1, true);
    w[2 * (base + c)]     = d0;
    w[2 * (base + c) + 1] = d1;
}

// FINAL (restores r13/r15, the session best: 192.4us bench / ~103us steady;
// session start was 279.6us bench / ~192us steady -> -46% kernel time).
// Ledger r0-r16, all counter-verified:
//   EXPLOITED: divergent-gather request/line reduction (r4 quad-pack -34%;
//     r11 fp8 row-pair -15%); occupancy 2->3 waves (r3); emb2 out of LDS
//     (r13: bank conflicts 1.59M->0, LDS 40KB).
//   FALSIFIED: 4 waves/SIMD — (256,4) compiler budget 128 < ~140 live set,
//     spilled 3x (r5/r6/r12); grid>768 at (256,3) never places a 4th block
//     even at 32KB LDS (r16) because HW reserves the DECLARED 170-reg
//     budget/wave: 2048/170 = 3 waves/SIMD, so excess blocks run as a
//     serial tail (r14/r16 occupancy DROPPED). VALU issue (r8: -18pp
//     VALUBusy, 0 dur). x-latency depth (r8). Gather placement (r9).
//     L2-miss service (r10: FETCH 316->37MB, 0 dur).
// Remaining ~45% issue-idle = per-wave dependency latency (serial LDS
// round-trips + MFMA chains) at a hardware-enforced 3-wave residency:
// the structural floor for this kernel shape.
__global__ __launch_bounds__(TPB, 3) void dgn_mfma(
    const float* __restrict__ x,
    const int2*  __restrict__ tabs,
    const float*  __restrict__ w1, const float* __restrict__ b1,
    const float*  __restrict__ w2, const float* __restrict__ b2,
    const float*  __restrict__ w3, const float* __restrict__ b3,
    float*        __restrict__ out, int npts)
{
    __shared__ __align__(16) _Float16 smem[4 * 4096];   // 4 waves * 8KB, wave-private
    __shared__ __align__(16) _Float16 w2l[4096];        // 8KB shared w2 fragments

    const int2* p0 = tabs;
    const int2* p1 = tabs + N0E;
    const int2* p2 = tabs + N0E + N1E;

    const int tid  = threadIdx.x;
    const int lane = tid & 63;
    const int wv   = tid >> 6;
    const int l15  = lane & 15;
    const int quad = lane >> 4;

    // ---- one-time staging: w2 fragments (swizzled) ----
    for (int e = tid; e < 4096; e += TPB) {
        int nt = e >> 10, rem = e & 1023, lw = rem >> 6, s = rem & 63;
        int oh = ((s & 3) << 4) | (s >> 2);             // sigma^{-1}
        w2l[nt * 1024 + lw * 64 + (s ^ ((lw & 7) << 3))] =
            (_Float16)w2[oh * 64 + nt * 16 + lw];
    }
    __syncthreads();

    // ---- persistent weight fragments. w1 K-permutation: slot k<12 -> row k+1
    // (features), slot 12 -> row 0 (idf), slots 13-15 -> zero. ----
    half8 w1f[4];
    #pragma unroll
    for (int nt = 0; nt < 4; ++nt)
        #pragma unroll
        for (int j = 0; j < 8; ++j) {
            int k = quad * 8 + j;
            int row = (k < 12) ? (k + 1) : ((k == 12) ? 0 : -1);
            w1f[nt][j] = (row >= 0) ? (_Float16)w1[row * 64 + nt * 16 + l15] : (_Float16)0.0f;
        }
    float b1v[4], b2v[4];
    #pragma unroll
    for (int nt = 0; nt < 4; ++nt) { b1v[nt] = b1[nt * 16 + l15]; b2v[nt] = b2[nt * 16 + l15]; }
    half8 w3f[2];
    #pragma unroll
    for (int ks = 0; ks < 2; ++ks)
        #pragma unroll
        for (int j = 0; j < 8; ++j) {
            int s  = ks * 32 + quad * 8 + j;
            int oh = ((s & 3) << 4) | (s >> 2);
            w3f[ks][j] = (l15 < 3) ? (_Float16)w3[oh * 3 + l15] : (_Float16)0.0f;
        }
    const float qsel = (quad == 0) ? 1.0f : 0.0f;
    const float qb30 = qsel * b3[0], qb31 = qsel * b3[1], qb32 = qsel * b3[2];

    // ---- precomputed LDS addresses (half-element units) ----
    const int bufh = wv * 4096;
    const int ewr0 = bufh + lane * 64 + ((lane & 7) ^ 0) * 8;
    const int ewr1 = bufh + lane * 64 + ((lane & 7) ^ 1) * 8;
    const int erd  = bufh + l15 * 64 + (quad ^ (l15 & 7)) * 8;          // quad<2 only
    int hwb[4];
    #pragma unroll
    for (int r = 0; r < 4; ++r) {
        int pr = quad * 4 + r;
        hwb[r] = bufh + pr * 64 + (((l15 >> 1) ^ (pr & 7)) * 8) + (l15 & 1) * 4;
    }
    int rd2[2];
    #pragma unroll
    for (int ks = 0; ks < 2; ++ks)
        rd2[ks] = bufh + l15 * 64 + (((ks * 4 + quad) ^ (l15 & 7)) * 8);
    int w2a[2];
    #pragma unroll
    for (int ks = 0; ks < 2; ++ks)
        w2a[ks] = l15 * 64 + (((ks * 4 + quad) ^ (l15 & 7)) * 8);

    const int ntiles = npts >> 8;
    const int gdim   = gridDim.x;

    // ---- prologue: tile-0 x + all three row-pair gathers in flight ----
    float cidf, cu, cv, wx0, wy0, wx1, wy1, wx2, wy2;
    intx4 t0q, t1q, t2q;
    {
        int pi = (blockIdx.x << 8) + (wv << 6) + lane;
        cidf = x[3 * pi]; cu = x[3 * pi + 1]; cv = x[3 * pi + 2];
        GQ g0 = gq(512, cu, cv); wx0 = g0.wx; wy0 = g0.wy;
        t0q = *(const intx4a*)&p0[g0.c];
        GQ g1 = gq(264, cu, cv); wx1 = g1.wx; wy1 = g1.wy;
        t1q = *(const intx4a*)&p1[g1.c];
        GQ g2 = gq(16, cu, cv); wx2 = g2.wx; wy2 = g2.wy;
        t2q = *(const intx4a*)&p2[g2.c];
    }

    for (int tile = blockIdx.x; tile < ntiles; tile += gdim) {
        // ---- features: fp8 decode + f32 lerp (2^-13 folded in y-weights) ----
        float f0[4], f1[4], f2[4];
        bil8(t0q, wx0, (1.0f - wy0) * INVSC, wy0 * INVSC, f0);
        bil8(t1q, wx1, (1.0f - wy1) * INVSC, wy1 * INVSC, f1);
        bil8(t2q, wx2, (1.0f - wy2) * INVSC, wy2 * INVSC, f2);
        // E pack: slots 0-11 = features, slot 12 = idf, 13-15 = 0
        union H8 { half8 v; h2 p[4]; } e0u, e1u;
        e0u.p[0] = pk2(f0[0], f0[1]); e0u.p[1] = pk2(f0[2], f0[3]);
        e0u.p[2] = pk2(f1[0], f1[1]); e0u.p[3] = pk2(f1[2], f1[3]);
        e1u.p[0] = pk2(f2[0], f2[1]); e1u.p[1] = pk2(f2[2], f2[3]);
        e1u.p[2] = pk2(cidf, 0.0f);   e1u.p[3] = pk2(0.0f, 0.0f);
        *(half8*)&smem[ewr0] = e0u.v;
        *(half8*)&smem[ewr1] = e1u.v;

        // ---- prefetch next tile's x (latency hidden by layer 1) ----
        int nxt = tile + gdim;
        int ptn = (((nxt < ntiles) ? nxt : tile) << 8) + (wv << 6) + lane;
        float nidf = x[3 * ptn], nu = x[3 * ptn + 1], nv = x[3 * ptn + 2];

        // ---- layer 1: K=32 (quads 2-3 feed zeros), bias in C-init ----
        #pragma unroll
        for (int mt = 0; mt < 4; ++mt) {
            half8 ea = { (_Float16)0, (_Float16)0, (_Float16)0, (_Float16)0,
                         (_Float16)0, (_Float16)0, (_Float16)0, (_Float16)0 };
            if (quad < 2) ea = *(const half8*)&smem[erd + mt * 1024];
            floatx4 acc[4];
            #pragma unroll
            for (int nt = 0; nt < 4; ++nt) {
                acc[nt] = (floatx4){ b1v[nt], b1v[nt], b1v[nt], b1v[nt] };
                acc[nt] = __builtin_amdgcn_mfma_f32_16x16x32_f16(ea, w1f[nt], acc[nt], 0, 0, 0);
            }
            #pragma unroll
            for (int r = 0; r < 4; ++r)
                *(half4*)&smem[hwb[r] + mt * 1024] =
                    relu_pk4(acc[0][r], acc[1][r], acc[2][r], acc[3][r]);
        }

        // ---- issue next tile's gathers (hidden by layers 2-3) ----
        float nwx0, nwy0, nwx1, nwy1, nwx2, nwy2;
        intx4 m0q, m1q, m2q;
        {
            GQ g0 = gq(512, nu, nv); nwx0 = g0.wx; nwy0 = g0.wy;
            m0q = *(const intx4a*)&p0[g0.c];
            GQ g1 = gq(264, nu, nv); nwx1 = g1.wx; nwy1 = g1.wy;
            m1q = *(const intx4a*)&p1[g1.c];
            GQ g2 = gq(16, nu, nv); nwx2 = g2.wx; nwy2 = g2.wy;
            m2q = *(const intx4a*)&p2[g2.c];
        }

        // ---- layer 2 (K=64): w2 frags reloaded phase-locally from LDS ----
        half8 w2r[4][2];
        #pragma unroll
        for (int nt = 0; nt < 4; ++nt)
            #pragma unroll
            for (int ks = 0; ks < 2; ++ks)
                w2r[nt][ks] = *(const half8*)&w2l[nt * 1024 + w2a[ks]];
        #pragma unroll
        for (int mt = 0; mt < 4; ++mt) {
            floatx4 acc[4];
            #pragma unroll
            for (int nt = 0; nt < 4; ++nt)
                acc[nt] = (floatx4){ b2v[nt], b2v[nt], b2v[nt], b2v[nt] };
            #pragma unroll
            for (int ks = 0; ks < 2; ++ks) {
                half8 a2 = *(const half8*)&smem[rd2[ks] + mt * 1024];
                #pragma unroll
                for (int nt = 0; nt < 4; ++nt)
                    acc[nt] = __builtin_amdgcn_mfma_f32_16x16x32_f16(a2, w2r[nt][ks], acc[nt], 0, 0, 0);
            }
            #pragma unroll
            for (int r = 0; r < 4; ++r)
                *(half4*)&smem[hwb[r] + mt * 1024] =
                    relu_pk4(acc[0][r], acc[1][r], acc[2][r], acc[3][r]);
        }

        // ---- layer 3 (transposed) ----
        #pragma unroll
        for (int mt = 0; mt < 4; ++mt) {
            floatx4 acc3 = (floatx4){ qb30, qb31, qb32, 0.0f };
            #pragma unroll
            for (int ks = 0; ks < 2; ++ks) {
                half8 bfr = *(const half8*)&smem[rd2[ks] + mt * 1024];
                acc3 = __builtin_amdgcn_mfma_f32_16x16x32_f16(w3f[ks], bfr, acc3, 0, 0, 0);
            }
            if (quad == 0) {
                const int P = (tile << 8) + (wv << 6) + mt * 16 + l15;
                out[3 * P + 0] = acc3[0];
                out[3 * P + 1] = acc3[1];
                out[3 * P + 2] = acc3[2];
            }
        }

        // ---- rotate pipeline registers ----
        cidf = nidf; cu = nu; cv = nv;
        wx0 = nwx0; wy0 = nwy0; wx1 = nwx1; wy1 = nwy1; wx2 = nwx2; wy2 = nwy2;
        t0q = m0q; t1q = m1q; t2q = m2q;
    }
}

// ---- fallback (validated round-3 kernel, float4 gathers) for tiny ws ----
__global__ __launch_bounds__(TPB, 3) void dgn_mfma_fb(
    const float*  __restrict__ x,
    const float4* __restrict__ emb0,
    const float4* __restrict__ emb1,
    const float4* __restrict__ emb2,
    const float*  __restrict__ w1, const float* __restrict__ b1,
    const float*  __restrict__ w2, const float* __restrict__ b2,
    const float*  __restrict__ w3, const float* __restrict__ b3,
    float*        __restrict__ out, int npts)
{
    __shared__ __align__(16) _Float16 smem[4 * 4096];
    __shared__ __align__(16) _Float16 w2l[4096];

    const int tid  = threadIdx.x;
    const int lane = tid & 63;
    const int wv   = tid >> 6;
    const int l15  = lane & 15;
    const int quad = lane >> 4;

    for (int e = tid; e < 4096; e += TPB) {
        int nt = e >> 10, rem = e & 1023, lw = rem >> 6, s = rem & 63;
        int oh = ((s & 3) << 4) | (s >> 2);
        w2l[nt * 1024 + lw * 64 + (s ^ ((lw & 7) << 3))] =
            (_Float16)w2[oh * 64 + nt * 16 + lw];
    }
    __syncthreads();

    half8 w1f[4];
    #pragma unroll
    for (int nt = 0; nt < 4; ++nt)
        #pragma unroll
        for (int j = 0; j < 8; ++j) {
            int k = quad * 8 + j;
            w1f[nt][j] = (k < 13) ? (_Float16)w1[k * 64 + nt * 16 + l15] : (_Float16)0.0f;
        }
    float b1v[4], b2v[4];
    #pragma unroll
    for (int nt = 0; nt < 4; ++nt) { b1v[nt] = b1[nt * 16 + l15]; b2v[nt] = b2[nt * 16 + l15]; }
    half8 w3f[2];
    #pragma unroll
    for (int ks = 0; ks < 2; ++ks)
        #pragma unroll
        for (int j = 0; j < 8; ++j) {
            int s  = ks * 32 + quad * 8 + j;
            int oh = ((s & 3) << 4) | (s >> 2);
            w3f[ks][j] = (l15 < 3) ? (_Float16)w3[oh * 3 + l15] : (_Float16)0.0f;
        }
    const float qsel = (quad == 0) ? 1.0f : 0.0f;
    const float qb30 = qsel * b3[0], qb31 = qsel * b3[1], qb32 = qsel * b3[2];

    const int bufh = wv * 4096;
    const int ewr0 = bufh + lane * 64 + ((lane & 7) ^ 0) * 8;
    const int ewr1 = bufh + lane * 64 + ((lane & 7) ^ 1) * 8;
    const int erd  = bufh + l15 * 64 + (quad ^ (l15 & 7)) * 8;
    int hwb[4];
    #pragma unroll
    for (int r = 0; r < 4; ++r) {
        int pr = quad * 4 + r;
        hwb[r] = bufh + pr * 64 + (((l15 >> 1) ^ (pr & 7)) * 8) + (l15 & 1) * 4;
    }
    int rd2[2];
    #pragma unroll
    for (int ks = 0; ks < 2; ++ks)
        rd2[ks] = bufh + l15 * 64 + (((ks * 4 + quad) ^ (l15 & 7)) * 8);
    int w2a[2];
    #pragma unroll
    for (int ks = 0; ks < 2; ++ks)
        w2a[ks] = l15 * 64 + (((ks * 4 + quad) ^ (l15 & 7)) * 8);

    const int ntiles = npts >> 8;
    const int gdim   = gridDim.x;

    float cidf, cu, cv, wx0, wy0, wx1, wy1;
    float4 t00, t01, t02, t03, t10, t11, t12, t13;
    {
        int p0 = (blockIdx.x << 8) + (wv << 6) + lane;
        cidf = x[3 * p0]; cu = x[3 * p0 + 1]; cv = x[3 * p0 + 2];
        GAddr g0 = gaddr(512, cu, cv); wx0 = g0.wx; wy0 = g0.wy;
        t00 = emb0[g0.i00]; t01 = emb0[g0.i10]; t02 = emb0[g0.i01]; t03 = emb0[g0.i11];
        GAddr g1 = gaddr(264, cu, cv); wx1 = g1.wx; wy1 = g1.wy;
        t10 = emb1[g1.i00]; t11 = emb1[g1.i10]; t12 = emb1[g1.i01]; t13 = emb1[g1.i11];
    }

    for (int tile = blockIdx.x; tile < ntiles; tile += gdim) {
        float f[12];
        bil4(t00, t01, t02, t03, wx0, wy0, f);
        bil4(t10, t11, t12, t13, wx1, wy1, f + 4);
        {
            GAddr g2 = gaddr(16, cu, cv);
            bil4(emb2[g2.i00], emb2[g2.i10], emb2[g2.i01], emb2[g2.i11], g2.wx, g2.wy, f + 8);
        }
        union H8 { half8 v; fp16x2 p[4]; } e0u, e1u;
        e0u.p[0] = __builtin_amdgcn_cvt_pkrtz(cidf, f[0]);
        e0u.p[1] = __builtin_amdgcn_cvt_pkrtz(f[1], f[2]);
        e0u.p[2] = __builtin_amdgcn_cvt_pkrtz(f[3], f[4]);
        e0u.p[3] = __builtin_amdgcn_cvt_pkrtz(f[5], f[6]);
        e1u.p[0] = __builtin_amdgcn_cvt_pkrtz(f[7], f[8]);
        e1u.p[1] = __builtin_amdgcn_cvt_pkrtz(f[9], f[10]);
        e1u.p[2] = __builtin_amdgcn_cvt_pkrtz(f[11], 0.0f);
        e1u.p[3] = __builtin_amdgcn_cvt_pkrtz(0.0f, 0.0f);
        *(half8*)&smem[ewr0] = e0u.v;
        *(half8*)&smem[ewr1] = e1u.v;

        int nxt = tile + gdim;
        int ptn = (((nxt < ntiles) ? nxt : tile) << 8) + (wv << 6) + lane;
        float nidf = x[3 * ptn], nu = x[3 * ptn + 1], nv = x[3 * ptn + 2];

        #pragma unroll
        for (int mt = 0; mt < 4; ++mt) {
            half8 ea = { (_Float16)0, (_Float16)0, (_Float16)0, (_Float16)0,
                         (_Float16)0, (_Float16)0, (_Float16)0, (_Float16)0 };
            if (quad < 2) ea = *(const half8*)&smem[erd + mt * 1024];
            floatx4 acc[4];
            #pragma unroll
            for (int nt = 0; nt < 4; ++nt) {
                acc[nt] = (floatx4){ b1v[nt], b1v[nt], b1v[nt], b1v[nt] };
                acc[nt] = __builtin_amdgcn_mfma_f32_16x16x32_f16(ea, w1f[nt], acc[nt], 0, 0, 0);
            }
            #pragma unroll
            for (int r = 0; r < 4; ++r)
                *(half4*)&smem[hwb[r] + mt * 1024] =
                    relu_pk4f(acc[0][r], acc[1][r], acc[2][r], acc[3][r]);
        }

        float nwx0, nwy0, nwx1, nwy1;
        float4 n00, n01, n02, n03, n10, n11, n12, n13;
        {
            GAddr g0 = gaddr(512, nu, nv); nwx0 = g0.wx; nwy0 = g0.wy;
            n00 = emb0[g0.i00]; n01 = emb0[g0.i10]; n02 = emb0[g0.i01]; n03 = emb0[g0.i11];
            GAddr g1 = gaddr(264, nu, nv); nwx1 = g1.wx; nwy1 = g1.wy;
            n10 = emb1[g1.i00]; n11 = emb1[g1.i10]; n12 = emb1[g1.i01]; n13 = emb1[g1.i11];
        }

        half8 w2r[4][2];
        #pragma unroll
        for (int nt = 0; nt < 4; ++nt)
            #pragma unroll
            for (int ks = 0; ks < 2; ++ks)
                w2r[nt][ks] = *(const half8*)&w2l[nt * 1024 + w2a[ks]];
        #pragma unroll
        for (int mt = 0; mt < 4; ++mt) {
            floatx4 acc[4];
            #pragma unroll
            for (int nt = 0; nt < 4; ++nt)
                acc[nt] = (floatx4){ b2v[nt], b2v[nt], b2v[nt], b2v[nt] };
            #pragma unroll
            for (int ks = 0; ks < 2; ++ks) {
                half8 a2 = *(const half8*)&smem[rd2[ks] + mt * 1024];
                #pragma unroll
                for (int nt = 0; nt < 4; ++nt)
                    acc[nt] = __builtin_amdgcn_mfma_f32_16x16x32_f16(a2, w2r[nt][ks], acc[nt], 0, 0, 0);
            }
            #pragma unroll
            for (int r = 0; r < 4; ++r)
                *(half4*)&smem[hwb[r] + mt * 1024] =
                    relu_pk4f(acc[0][r], acc[1][r], acc[2][r], acc[3][r]);
        }

        #pragma unroll
        for (int mt = 0; mt < 4; ++mt) {
            floatx4 acc3 = (floatx4){ qb30, qb31, qb32, 0.0f };
            #pragma unroll
            for (int ks = 0; ks < 2; ++ks) {
                half8 bfr = *(const half8*)&smem[rd2[ks] + mt * 1024];
                acc3 = __builtin_amdgcn_mfma_f32_16x16x32_f16(w3f[ks], bfr, acc3, 0, 0, 0);
            }
            if (quad == 0) {
                const int P = (tile << 8) + (wv << 6) + mt * 16 + l15;
                out[3 * P + 0] = acc3[0];
                out[3 * P + 1] = acc3[1];
                out[3 * P + 2] = acc3[2];
            }
        }

        cidf = nidf; cu = nu; cv = nv;
        wx0 = nwx0; wy0 = nwy0; wx1 = nwx1; wy1 = nwy1;
        t00 = n00; t01 = n01; t02 = n02; t03 = n03;
        t10 = n10; t11 = n11; t12 = n12; t13 = n13;
    }
}

extern "C" void kernel_launch(void* const* d_in, const int* in_sizes, int n_in,
                              void* d_out, int out_size, void* d_ws, size_t ws_size,
                              hipStream_t stream) {
    const float*  x    = (const float*)  d_in[0];
    const float4* emb0 = (const float4*) d_in[1];
    const float4* emb1 = (const float4*) d_in[2];
    const float4* emb2 = (const float4*) d_in[3];
    const float*  w1   = (const float*)  d_in[4];
    const float*  b1   = (const float*)  d_in[5];
    const float*  w2   = (const float*)  d_in[6];
    const float*  b2   = (const float*)  d_in[7];
    const float*  w3   = (const float*)  d_in[8];
    const float*  b3   = (const float*)  d_in[9];
    float* out = (float*)d_out;

    int npts = in_sizes[0] / 3;
    const size_t need = (size_t)(N0E + N1E + N2E) * 8;   // ~2.7 MB

    if (d_ws != nullptr && ws_size >= need) {
        int work = N0E + N1E + N2E;
        pack_tables<<<(work + 255) / 256, 256, 0, stream>>>(emb0, emb1, emb2, (int*)d_ws);
        // grid 768 = 3 blocks/CU: the proven optimum. 4 blocks/CU is closed
        // from both directions: (256,4) compiler budget spills; at (256,3)
        // the HW reserves the declared 170-reg budget (2048/170 = 3 waves/
        // SIMD) so grid>768 runs a serial tail (r14/r16: occupancy dropped).
        dgn_mfma<<<768, TPB, 0, stream>>>(x, (const int2*)d_ws,
                                          w1, b1, w2, b2, w3, b3, out, npts);
    } else {
        dgn_mfma_fb<<<768, TPB, 0, stream>>>(x, emb0, emb1, emb2,
                                             w1, b1, w2, b2, w3, b3, out, npts);
    }
}